// Round 4
// baseline (1469.033 us; speedup 1.0000x reference)
//
#include <hip/hip_runtime.h>
#include <math.h>

typedef __attribute__((ext_vector_type(8))) short short8;
typedef __attribute__((ext_vector_type(4))) short short4v;
typedef __attribute__((ext_vector_type(4))) float f32x4;

union U32S8 { unsigned u[4]; short8 s8; ushort e[8]; short4v h[2]; };

#define BATCH 128
#define NHIS  50
#define NCAND 5
#define KP    320   // padded K stride for transposed weights (elems)
#define XS    328   // CTX LDS row stride
#define NQKV  912   // padded N for [Wq|Wk|Wv]
#define NWP   208   // padded N for Wp
#define NQ    900   // valid QKV cols
#define SCALE 0.22360679774997896f  // 1/sqrt(20)

__device__ __forceinline__ ushort f2bf(float f) {
    union { float f; unsigned u; } v; v.f = f;
    return (ushort)((v.u + 0x7fffu + ((v.u >> 16) & 1u)) >> 16);
}
__device__ __forceinline__ unsigned pack2bf(float lo, float hi) {
    return (unsigned)f2bf(lo) | ((unsigned)f2bf(hi) << 16);
}
__device__ __forceinline__ float bf2f(ushort u) {
    union { float f; unsigned u; } v; v.u = ((unsigned)u) << 16;
    return v.f;
}

// ---------- weight prep: W[k][n] fp32 -> WT[p][n][k] bf16, zero-padded ----------
__global__ void prep_qkv(const float* __restrict__ Wq, const float* __restrict__ Wk,
                         const float* __restrict__ Wv, ushort* __restrict__ dst, int P) {
    size_t i = (size_t)blockIdx.x * 256 + threadIdx.x;
    size_t total = (size_t)P * NQKV * KP;
    if (i >= total) return;
    int k = (int)(i % KP);
    int n = (int)((i / KP) % NQKV);
    int p = (int)(i / ((size_t)KP * NQKV));
    float v = 0.f;
    if (k < 300 && n < 900) {
        const float* W = (n < 300) ? Wq : (n < 600 ? Wk : Wv);
        int nn = n % 300;
        v = W[((size_t)p * 300 + k) * 300 + nn];
    }
    dst[i] = f2bf(v);
}

__global__ void prep_wp(const float* __restrict__ Wp, ushort* __restrict__ dst, int P) {
    size_t i = (size_t)blockIdx.x * 256 + threadIdx.x;
    size_t total = (size_t)P * NWP * KP;
    if (i >= total) return;
    int k = (int)(i % KP);
    int a = (int)((i / KP) % NWP);
    int p = (int)(i / ((size_t)KP * NWP));
    float v = 0.f;
    if (k < 300 && a < 200) v = Wp[((size_t)p * 300 + k) * 200 + a];
    dst[i] = f2bf(v);
}

// ---------- K2: batched QKV GEMM per p ----------
// Per p: [3840 x 320] (gathered emb rows, bf16) x [320 x 912] (WT^T) -> qkv [3840][900] bf16.
// grid: P_chunk * 30(mtile) * 8(ntile), ntile innermost (L2 A-reuse). 256 th, 4 waves,
// each wave owns a 64x64 quadrant (4x4 fragments).
__global__ __launch_bounds__(256, 4)
void qkv_gemm(const float* __restrict__ emb, const int* __restrict__ tokens,
              const ushort* __restrict__ wt,   // [P_all][NQKV][KP]
              ushort* __restrict__ qkv,        // [P_chunk][3840][900]
              int p0, int P_all)
{
    __shared__ ushort At[2][128][40];
    __shared__ ushort Bt[2][128][40];
    __shared__ int TOK[128];

    const int bid   = blockIdx.x;
    const int ntile = bid & 7;
    const int mtile = (bid >> 3) % 30;
    const int p_l   = bid / 240;
    const int p_g   = p0 + p_l;
    const int t     = threadIdx.x;
    const int wave  = t >> 6, lane = t & 63;
    const int r = lane & 15, g = lane >> 4;
    const int qm = wave >> 1, qn = wave & 1;

    if (t < 128) {
        int row = mtile * 128 + t;
        int b = row / 30, l = row - b * 30;
        TOK[t] = tokens[((size_t)b * P_all + p_g) * 30 + l];
    }
    __syncthreads();

    const ushort* wtp = wt + (size_t)p_g * NQKV * KP;
    const int rr = t >> 1, half = t & 1;

    // stage kstep ks into buffer buf
    auto stage = [&](int ks, int buf) {
        // A: emb[TOK[rr]][ks*32 + half*16 .. +16) fp32 -> bf16
        {
            int base = ks * 32 + half * 16;
            ushort* dst = &At[buf][rr][half * 16];
            const float* src = emb + (size_t)TOK[rr] * 300 + base;
            if (base + 16 <= 300) {
                float4 v0 = *(const float4*)(src);
                float4 v1 = *(const float4*)(src + 4);
                float4 v2 = *(const float4*)(src + 8);
                float4 v3 = *(const float4*)(src + 12);
                unsigned* d = (unsigned*)dst;
                d[0] = pack2bf(v0.x, v0.y); d[1] = pack2bf(v0.z, v0.w);
                d[2] = pack2bf(v1.x, v1.y); d[3] = pack2bf(v1.z, v1.w);
                d[4] = pack2bf(v2.x, v2.y); d[5] = pack2bf(v2.z, v2.w);
                d[6] = pack2bf(v3.x, v3.y); d[7] = pack2bf(v3.z, v3.w);
            } else {
                #pragma unroll
                for (int c = 0; c < 16; ++c)
                    dst[c] = (base + c < 300) ? f2bf(src[c]) : (ushort)0;
            }
        }
        // B: WT row n = ntile*128 + rr, same k slice (already bf16, pre-padded)
        {
            int n = ntile * 128 + rr;
            ushort* dst = &Bt[buf][rr][half * 16];
            if (n < NQKV) {
                const ushort* srcb = wtp + (size_t)n * KP + ks * 32 + half * 16;
                ((short8*)dst)[0] = ((const short8*)srcb)[0];
                ((short8*)dst)[1] = ((const short8*)srcb)[1];
            } else {
                short8 z = {0,0,0,0,0,0,0,0};
                ((short8*)dst)[0] = z;
                ((short8*)dst)[1] = z;
            }
        }
    };

    f32x4 acc[4][4];
    #pragma unroll
    for (int i = 0; i < 4; ++i)
        #pragma unroll
        for (int j = 0; j < 4; ++j)
            acc[i][j] = (f32x4){0.f, 0.f, 0.f, 0.f};

    stage(0, 0);
    __syncthreads();
    int buf = 0;
    for (int ks = 0; ks < 10; ++ks) {
        if (ks < 9) stage(ks + 1, buf ^ 1);
        // compute on buf
        short8 af[4], bfr[4];
        #pragma unroll
        for (int fi = 0; fi < 4; ++fi)
            af[fi] = *(const short8*)&At[buf][qm * 64 + fi * 16 + r][8 * g];
        #pragma unroll
        for (int fj = 0; fj < 4; ++fj)
            bfr[fj] = *(const short8*)&Bt[buf][qn * 64 + fj * 16 + r][8 * g];
        #pragma unroll
        for (int fi = 0; fi < 4; ++fi)
            #pragma unroll
            for (int fj = 0; fj < 4; ++fj)
                acc[fi][fj] = __builtin_amdgcn_mfma_f32_16x16x32_bf16(af[fi], bfr[fj], acc[fi][fj], 0, 0, 0);
        __syncthreads();
        buf ^= 1;
    }

    // epilogue: D[4g+j][r] -> qkv[p_l][row][n]
    ushort* outp = qkv + (size_t)p_l * 3840 * NQ;
    #pragma unroll
    for (int fi = 0; fi < 4; ++fi) {
        #pragma unroll
        for (int fj = 0; fj < 4; ++fj) {
            int n = ntile * 128 + qn * 64 + fj * 16 + r;
            if (n < NQ) {
                #pragma unroll
                for (int j = 0; j < 4; ++j) {
                    int row = mtile * 128 + qm * 64 + fi * 16 + 4 * g + j;
                    outp[(size_t)row * NQ + n] = f2bf(acc[fi][fj][j]);
                }
            }
        }
    }
}

// ---------- K3: attention + pooling per instance ----------
__device__ __forceinline__ short8 load_qk_frag(const ushort* rowptr, int colbase, int g, bool rowvalid) {
    // elements i: col = colbase + i; valid iff rowvalid && 8g+i < 20. colbase is 8B-aligned.
    U32S8 v;
    v.s8 = (short8){0,0,0,0,0,0,0,0};
    if (rowvalid && g < 3) {
        const ushort* src = rowptr + colbase;
        if (g < 2) {
            v.h[0] = *(const short4v*)src;
            v.h[1] = *(const short4v*)(src + 4);
        } else {
            v.h[0] = *(const short4v*)src;   // elems 16..19
        }
    }
    return v.s8;
}

__global__ __launch_bounds__(512, 1)
void attn_pool(const ushort* __restrict__ qkv,    // [P_chunk][3840][900]
               const ushort* __restrict__ wt_wp,  // [P_all][NWP][KP]
               const float* __restrict__ bp, const float* __restrict__ qv,
               float* __restrict__ out,           // [B][P_all][300]
               int p0, int P_all)
{
    __shared__ ushort ctx[32 * XS];   // 21 KB
    __shared__ float  SL[64];

    const int tid  = threadIdx.x;
    const int wave = tid >> 6;
    const int lane = tid & 63;
    const int r = lane & 15, g = lane >> 4;
    const int p_l = blockIdx.x / BATCH;   // p-major: co-resident blocks share Wp
    const int b   = blockIdx.x % BATCH;
    const int p_g = p0 + p_l;

    for (int i = tid; i < 32 * XS; i += 512) ctx[i] = 0;
    if (tid < 64) SL[tid] = 0.f;
    __syncthreads();

    const ushort* qb = qkv + ((size_t)p_l * 3840 + (size_t)b * 30) * NQ;

    #pragma unroll
    for (int hp = 0; hp < 2; ++hp) {
        int head = wave + 8 * hp;
        if (head < 15) {
            // Q/K fragments from global (masked k-pad 20->32)
            short8 q0 = load_qk_frag(qb + (size_t)(r) * NQ,      head * 20 + 8 * g, g, r < 30);
            short8 q1 = load_qk_frag(qb + (size_t)(16 + r) * NQ, head * 20 + 8 * g, g, 16 + r < 30);
            short8 k0 = load_qk_frag(qb + (size_t)(r) * NQ,      300 + head * 20 + 8 * g, g, r < 30);
            short8 k1 = load_qk_frag(qb + (size_t)(16 + r) * NQ, 300 + head * 20 + 8 * g, g, 16 + r < 30);
            // V fragments: vf[nt] elem i = V[m=8g+i][head*20 + nt*16 + r]
            U32S8 vf0, vf1;
            vf0.s8 = (short8){0,0,0,0,0,0,0,0};
            vf1.s8 = vf0.s8;
            {
                int vj = r;   // nt=0
                const ushort* vsrc = qb + 600 + head * 20 + vj;
                #pragma unroll
                for (int i = 0; i < 8; ++i) {
                    int m = 8 * g + i;
                    if (m < 30) vf0.e[i] = vsrc[(size_t)m * NQ];
                }
            }
            if (16 + r < 20) {
                int vj = 16 + r;  // nt=1
                const ushort* vsrc = qb + 600 + head * 20 + vj;
                #pragma unroll
                for (int i = 0; i < 8; ++i) {
                    int m = 8 * g + i;
                    if (m < 30) vf1.e[i] = vsrc[(size_t)m * NQ];
                }
            }

            // S^T = K.Q^T : s{qt}m{kt}[j] = S[l=qt*16+r][m=kt*16+4g+j]
            f32x4 s0m0 = {0,0,0,0}, s0m1 = {0,0,0,0}, s1m0 = {0,0,0,0}, s1m1 = {0,0,0,0};
            s0m0 = __builtin_amdgcn_mfma_f32_16x16x32_bf16(k0, q0, s0m0, 0, 0, 0);
            s0m1 = __builtin_amdgcn_mfma_f32_16x16x32_bf16(k1, q0, s0m1, 0, 0, 0);
            s1m0 = __builtin_amdgcn_mfma_f32_16x16x32_bf16(k0, q1, s1m0, 0, 0, 0);
            s1m1 = __builtin_amdgcn_mfma_f32_16x16x32_bf16(k1, q1, s1m1, 0, 0, 0);

            float mx0 = -1e30f, mx1 = -1e30f;
            #pragma unroll
            for (int j = 0; j < 4; ++j) {
                s0m0[j] *= SCALE; s1m0[j] *= SCALE;
                float v01 = (16 + 4 * g + j < 30) ? s0m1[j] * SCALE : -1e30f;
                float v11 = (16 + 4 * g + j < 30) ? s1m1[j] * SCALE : -1e30f;
                s0m1[j] = v01; s1m1[j] = v11;
                mx0 = fmaxf(mx0, fmaxf(s0m0[j], v01));
                mx1 = fmaxf(mx1, fmaxf(s1m0[j], v11));
            }
            mx0 = fmaxf(mx0, __shfl_xor(mx0, 16, 64));
            mx0 = fmaxf(mx0, __shfl_xor(mx0, 32, 64));
            mx1 = fmaxf(mx1, __shfl_xor(mx1, 16, 64));
            mx1 = fmaxf(mx1, __shfl_xor(mx1, 32, 64));
            float sm0 = 0.f, sm1 = 0.f;
            #pragma unroll
            for (int j = 0; j < 4; ++j) {
                s0m0[j] = __expf(s0m0[j] - mx0); s0m1[j] = __expf(s0m1[j] - mx0);
                s1m0[j] = __expf(s1m0[j] - mx1); s1m1[j] = __expf(s1m1[j] - mx1);
                sm0 += s0m0[j] + s0m1[j];
                sm1 += s1m0[j] + s1m1[j];
            }
            sm0 += __shfl_xor(sm0, 16, 64); sm0 += __shfl_xor(sm0, 32, 64);
            sm1 += __shfl_xor(sm1, 16, 64); sm1 += __shfl_xor(sm1, 32, 64);
            float inv0 = 1.0f / sm0, inv1 = 1.0f / sm1;

            unsigned pk000 = pack2bf(s0m0[0] * inv0, s0m0[1] * inv0);
            unsigned pk001 = pack2bf(s0m0[2] * inv0, s0m0[3] * inv0);
            unsigned pk010 = pack2bf(s0m1[0] * inv0, s0m1[1] * inv0);
            unsigned pk011 = pack2bf(s0m1[2] * inv0, s0m1[3] * inv0);
            unsigned pk100 = pack2bf(s1m0[0] * inv1, s1m0[1] * inv1);
            unsigned pk101 = pack2bf(s1m0[2] * inv1, s1m0[3] * inv1);
            unsigned pk110 = pack2bf(s1m1[0] * inv1, s1m1[1] * inv1);
            unsigned pk111 = pack2bf(s1m1[2] * inv1, s1m1[3] * inv1);

            const int sA = r + 16 * (2 * (g & 1));
            const int sB = sA + 16;
            const bool hi = (g >> 1) != 0;
            #pragma unroll
            for (int lt = 0; lt < 2; ++lt) {
                unsigned q00 = lt ? pk100 : pk000, q01 = lt ? pk101 : pk001;
                unsigned q10 = lt ? pk110 : pk010, q11 = lt ? pk111 : pk011;
                unsigned a0 = __shfl((int)q00, sA, 64), a1 = __shfl((int)q01, sA, 64);
                unsigned a2 = __shfl((int)q10, sA, 64), a3 = __shfl((int)q11, sA, 64);
                unsigned b0 = __shfl((int)q00, sB, 64), b1 = __shfl((int)q01, sB, 64);
                unsigned b2 = __shfl((int)q10, sB, 64), b3 = __shfl((int)q11, sB, 64);
                U32S8 pf;
                pf.u[0] = hi ? a2 : a0;
                pf.u[1] = hi ? a3 : a1;
                pf.u[2] = hi ? b2 : b0;
                pf.u[3] = hi ? b3 : b1;
                int lrow = lt * 16 + r;
                #pragma unroll
                for (int nt = 0; nt < 2; ++nt) {
                    short8 vf = nt ? vf1.s8 : vf0.s8;
                    f32x4 c = {0.f, 0.f, 0.f, 0.f};
                    c = __builtin_amdgcn_mfma_f32_16x16x32_bf16(vf, pf.s8, c, 0, 0, 0);
                    if (lrow < 30) {
                        #pragma unroll
                        for (int j = 0; j < 4; ++j) {
                            int vj = nt * 16 + 4 * g + j;
                            if (vj < 20)
                                ctx[lrow * XS + head * 20 + vj] = f2bf(c[j]);
                        }
                    }
                }
            }
        }
    }
    __syncthreads();

    // ---- pooling: tanh(ctx @ Wp + bp) . qv ----
    const ushort* wp = wt_wp + (size_t)p_g * NWP * KP;
    for (int nt = wave; nt < 13; nt += 8) {
        const ushort* wrow = wp + (size_t)(nt * 16 + r) * KP + 8 * g;
        short8 breg[10];
        #pragma unroll
        for (int ks = 0; ks < 10; ++ks) breg[ks] = *(const short8*)(wrow + 32 * ks);
        int ai = nt * 16 + r;
        float bpv = (ai < 200) ? bp[p_g * 200 + ai] : 0.f;
        float qvv = (ai < 200) ? qv[p_g * 200 + ai] : 0.f;
        #pragma unroll
        for (int mt = 0; mt < 2; ++mt) {
            f32x4 acc = {0.f, 0.f, 0.f, 0.f};
            const ushort* crow = &ctx[(mt * 16 + r) * XS + 8 * g];
            #pragma unroll
            for (int ks = 0; ks < 10; ++ks) {
                short8 a = *(const short8*)(crow + 32 * ks);
                acc = __builtin_amdgcn_mfma_f32_16x16x32_bf16(a, breg[ks], acc, 0, 0, 0);
            }
            if (ai < 200) {
                #pragma unroll
                for (int j = 0; j < 4; ++j)
                    atomicAdd(&SL[mt * 16 + 4 * g + j], tanhf(acc[j] + bpv) * qvv);
            }
        }
    }
    __syncthreads();
    if (tid == 0) {
        float mx = -1e30f;
        for (int l = 0; l < 30; ++l) mx = fmaxf(mx, SL[l]);
        float s = 0.f;
        for (int l = 0; l < 30; ++l) { float e = __expf(SL[l] - mx); SL[l] = e; s += e; }
        float inv = 1.0f / s;
        for (int l = 0; l < 30; ++l) SL[l] *= inv;
    }
    __syncthreads();
    for (int c = tid; c < 300; c += 512) {
        float o = 0.f;
        for (int l = 0; l < 30; ++l) o = fmaf(SL[l], bf2f(ctx[l * XS + c]), o);
        out[((size_t)b * P_all + p_g) * 300 + c] = o;
    }
}

// ---------- user encoder, L=50 (R3, unchanged) ----------
#define QS 488
__global__ __launch_bounds__(512, 1)
void encode_user(const float* __restrict__ news_enc, const ushort* __restrict__ wt_qkv,
                 const ushort* __restrict__ wt_wp, const float* __restrict__ bp,
                 const float* __restrict__ qv, float* __restrict__ user_rep)
{
    __shared__ ushort Xb[64 * XS];
    __shared__ ushort Cb[64 * XS];
    __shared__ ushort Qh[64 * 32];
    __shared__ ushort Kh[64 * 32];
    __shared__ ushort VTh[32 * 64];
    __shared__ float  SC[64 * 64];
    __shared__ ushort Pb[64 * 64];
    __shared__ float  SL[64];

    const int tid  = threadIdx.x;
    const int wave = tid >> 6;
    const int lane = tid & 63;
    const int r = lane & 15, g = lane >> 4;
    const int b = blockIdx.x;

    for (int i = tid; i < 64 * XS; i += 512) { Xb[i] = 0; Cb[i] = 0; }
    for (int i = tid; i < 64 * 32; i += 512) { Qh[i] = 0; Kh[i] = 0; }
    for (int i = tid; i < 32 * 64; i += 512) VTh[i] = 0;
    for (int i = tid; i < 64 * 64; i += 512) Pb[i] = 0;
    if (tid < 64) SL[tid] = 0.f;
    __syncthreads();

    for (int i = tid; i < 50 * 300; i += 512) {
        int l = i / 300, d = i - l * 300;
        Xb[l * XS + d] = f2bf(news_enc[((size_t)b * 50 + l) * 300 + d]);
    }
    __syncthreads();

    for (int h = 0; h < 15; ++h) {
        const int nt = wave >> 2, mt = wave & 3;
        for (int seg = 0; seg < 3; ++seg) {
            f32x4 acc = {0.f, 0.f, 0.f, 0.f};
            int n = seg * 300 + h * 20 + nt * 16 + r;
            const ushort* wrow = wt_qkv + (size_t)n * KP + 8 * g;
            short8 breg[10];
            #pragma unroll
            for (int ks = 0; ks < 10; ++ks) breg[ks] = *(const short8*)(wrow + 32 * ks);
            const ushort* xrow = &Xb[(mt * 16 + r) * XS + 8 * g];
            #pragma unroll
            for (int ks = 0; ks < 10; ++ks) {
                short8 a = *(const short8*)(xrow + 32 * ks);
                acc = __builtin_amdgcn_mfma_f32_16x16x32_bf16(a, breg[ks], acc, 0, 0, 0);
            }
            int c = nt * 16 + r;
            if (c < 20) {
                #pragma unroll
                for (int j = 0; j < 4; ++j) {
                    int row = mt * 16 + 4 * g + j;
                    ushort v = f2bf(acc[j]);
                    if (seg == 0)      Qh[row * 32 + c] = v;
                    else if (seg == 1) Kh[row * 32 + c] = v;
                    else               VTh[c * 64 + row] = v;
                }
            }
        }
        __syncthreads();
        for (int it = 0; it < 2; ++it) {
            int tile = wave + 8 * it;
            int smt = tile & 3, snt = tile >> 2;
            short8 a  = *(const short8*)&Qh[(smt * 16 + r) * 32 + 8 * g];
            short8 bb = *(const short8*)&Kh[(snt * 16 + r) * 32 + 8 * g];
            f32x4 acc = {0.f, 0.f, 0.f, 0.f};
            acc = __builtin_amdgcn_mfma_f32_16x16x32_bf16(a, bb, acc, 0, 0, 0);
            #pragma unroll
            for (int j = 0; j < 4; ++j)
                SC[(smt * 16 + 4 * g + j) * 64 + snt * 16 + r] = acc[j] * SCALE;
        }
        __syncthreads();
        if (tid < 50) {
            float* row = &SC[tid * 64];
            float mx = -1e30f;
            for (int m = 0; m < 50; ++m) mx = fmaxf(mx, row[m]);
            float sum = 0.f;
            for (int m = 0; m < 50; ++m) { float e = __expf(row[m] - mx); row[m] = e; sum += e; }
            float inv = 1.0f / sum;
            ushort* prow = &Pb[tid * 64];
            for (int m = 0; m < 64; ++m) prow[m] = (m < 50) ? f2bf(row[m] * inv) : (ushort)0;
        }
        __syncthreads();
        {
            int cmt = wave & 3, cnt = wave >> 2;
            f32x4 acc = {0.f, 0.f, 0.f, 0.f};
            #pragma unroll
            for (int ks = 0; ks < 2; ++ks) {
                short8 a  = *(const short8*)&Pb[(cmt * 16 + r) * 64 + 32 * ks + 8 * g];
                short8 bb = *(const short8*)&VTh[(cnt * 16 + r) * 64 + 32 * ks + 8 * g];
                acc = __builtin_amdgcn_mfma_f32_16x16x32_bf16(a, bb, acc, 0, 0, 0);
            }
            int vj = cnt * 16 + r;
            if (vj < 20) {
                #pragma unroll
                for (int j = 0; j < 4; ++j)
                    Cb[(cmt * 16 + 4 * g + j) * XS + h * 20 + vj] = f2bf(acc[j]);
            }
        }
        __syncthreads();
    }

    for (int tile = wave; tile < 52; tile += 8) {
        int nt = tile >> 2, mt = tile & 3;
        f32x4 acc = {0.f, 0.f, 0.f, 0.f};
        const ushort* wrow = wt_wp + (size_t)(nt * 16 + r) * KP + 8 * g;
        short8 breg[10];
        #pragma unroll
        for (int ks = 0; ks < 10; ++ks) breg[ks] = *(const short8*)(wrow + 32 * ks);
        const ushort* crow = &Cb[(mt * 16 + r) * XS + 8 * g];
        #pragma unroll
        for (int ks = 0; ks < 10; ++ks) {
            short8 a = *(const short8*)(crow + 32 * ks);
            acc = __builtin_amdgcn_mfma_f32_16x16x32_bf16(a, breg[ks], acc, 0, 0, 0);
        }
        int ai = nt * 16 + r;
        if (ai < 200) {
            float bpv = bp[ai], qvv = qv[ai];
            #pragma unroll
            for (int j = 0; j < 4; ++j)
                atomicAdd(&SL[mt * 16 + 4 * g + j], tanhf(acc[j] + bpv) * qvv);
        }
    }
    __syncthreads();
    if (tid == 0) {
        float mx = -1e30f;
        for (int l = 0; l < 50; ++l) mx = fmaxf(mx, SL[l]);
        float s = 0.f;
        for (int l = 0; l < 50; ++l) { float e = __expf(SL[l] - mx); SL[l] = e; s += e; }
        float inv = 1.0f / s;
        for (int l = 0; l < 50; ++l) SL[l] *= inv;
    }
    __syncthreads();
    for (int c = tid; c < 300; c += 512) {
        float o = 0.f;
        for (int l = 0; l < 50; ++l) o = fmaf(SL[l], bf2f(Cb[l * XS + c]), o);
        user_rep[(size_t)b * 300 + c] = o;
    }
}

// ---------- final scoring ----------
__global__ __launch_bounds__(320)
void score_kernel(const float* __restrict__ user_rep, const float* __restrict__ cand_enc,
                  float* __restrict__ out)
{
    __shared__ float sc[NCAND];
    int b = blockIdx.x;
    int w = threadIdx.x >> 6;
    int lane = threadIdx.x & 63;
    float partial = 0.f;
    for (int d = lane; d < 300; d += 64)
        partial = fmaf(user_rep[b * 300 + d], cand_enc[((size_t)b * NCAND + w) * 300 + d], partial);
    for (int off = 32; off > 0; off >>= 1)
        partial += __shfl_down(partial, off, 64);
    if (lane == 0) sc[w] = partial;
    __syncthreads();
    if (threadIdx.x == 0) {
        float mx = -1e30f;
        for (int c = 0; c < NCAND; ++c) mx = fmaxf(mx, sc[c]);
        float s = 0.f; float e[NCAND];
        for (int c = 0; c < NCAND; ++c) { e[c] = __expf(sc[c] - mx); s += e[c]; }
        float inv = 1.0f / s;
        for (int c = 0; c < NCAND; ++c) out[b * NCAND + c] = e[c] * inv;
    }
}

extern "C" void kernel_launch(void* const* d_in, const int* in_sizes, int n_in,
                              void* d_out, int out_size, void* d_ws, size_t ws_size,
                              hipStream_t stream) {
    const int*   news_input = (const int*)d_in[0];
    const int*   candidates = (const int*)d_in[1];
    const float* emb        = (const float*)d_in[2];
    const float* his_Wq  = (const float*)d_in[3];
    const float* his_Wk  = (const float*)d_in[4];
    const float* his_Wv  = (const float*)d_in[5];
    const float* his_Wp  = (const float*)d_in[6];
    const float* his_bp  = (const float*)d_in[7];
    const float* his_qv  = (const float*)d_in[8];
    const float* cand_Wq = (const float*)d_in[9];
    const float* cand_Wk = (const float*)d_in[10];
    const float* cand_Wv = (const float*)d_in[11];
    const float* cand_Wp = (const float*)d_in[12];
    const float* cand_bp = (const float*)d_in[13];
    const float* cand_qv = (const float*)d_in[14];
    const float* usr_Wq  = (const float*)d_in[15];
    const float* usr_Wk  = (const float*)d_in[16];
    const float* usr_Wv  = (const float*)d_in[17];
    const float* usr_Wp  = (const float*)d_in[18];
    const float* usr_bp  = (const float*)d_in[19];
    const float* usr_qv  = (const float*)d_in[20];
    float* out = (float*)d_out;

    char* ws = (char*)d_ws;
    float* news_enc = (float*)ws;                 ws += (size_t)BATCH * NHIS * 300 * 4;
    float* cand_enc = (float*)ws;                 ws += (size_t)BATCH * NCAND * 300 * 4;
    float* user_rep = (float*)ws;                 ws += (size_t)BATCH * 300 * 4;
    ushort* his_qkvT  = (ushort*)ws;              ws += (size_t)NHIS * NQKV * KP * 2;
    ushort* his_wpT   = (ushort*)ws;              ws += (size_t)NHIS * NWP  * KP * 2;
    ushort* cand_qkvT = (ushort*)ws;              ws += (size_t)NCAND * NQKV * KP * 2;
    ushort* cand_wpT  = (ushort*)ws;              ws += (size_t)NCAND * NWP  * KP * 2;
    ushort* usr_qkvT  = (ushort*)ws;              ws += (size_t)NQKV * KP * 2;
    ushort* usr_wpT   = (ushort*)ws;              ws += (size_t)NWP  * KP * 2;
    ushort* qkv_ws    = (ushort*)ws;
    size_t used = (size_t)(ws - (char*)d_ws);
    size_t avail = (ws_size > used) ? (ws_size - used) : 0;
    size_t per_p = (size_t)3840 * NQ * 2;   // bytes per p of qkv intermediate
    // chunk size over p: prefer 50 (one pass), else 25, else 10
    int CP = 10;
    if (avail >= 50 * per_p) CP = 50;
    else if (avail >= 25 * per_p) CP = 25;

    auto blocks = [](size_t total) { return (int)((total + 255) / 256); };

    prep_qkv<<<blocks((size_t)NHIS  * NQKV * KP), 256, 0, stream>>>(his_Wq,  his_Wk,  his_Wv,  his_qkvT,  NHIS);
    prep_qkv<<<blocks((size_t)NCAND * NQKV * KP), 256, 0, stream>>>(cand_Wq, cand_Wk, cand_Wv, cand_qkvT, NCAND);
    prep_qkv<<<blocks((size_t)1     * NQKV * KP), 256, 0, stream>>>(usr_Wq,  usr_Wk,  usr_Wv,  usr_qkvT,  1);
    prep_wp <<<blocks((size_t)NHIS  * NWP  * KP), 256, 0, stream>>>(his_Wp,  his_wpT,  NHIS);
    prep_wp <<<blocks((size_t)NCAND * NWP  * KP), 256, 0, stream>>>(cand_Wp, cand_wpT, NCAND);
    prep_wp <<<blocks((size_t)1     * NWP  * KP), 256, 0, stream>>>(usr_Wp,  usr_wpT,  1);

    // news encoder: chunked over p
    for (int p0 = 0; p0 < NHIS; p0 += CP) {
        int cp = (NHIS - p0 < CP) ? (NHIS - p0) : CP;
        qkv_gemm<<<cp * 240, 256, 0, stream>>>(emb, news_input, his_qkvT, qkv_ws, p0, NHIS);
        attn_pool<<<cp * BATCH, 512, 0, stream>>>(qkv_ws, his_wpT, his_bp, his_qv, news_enc, p0, NHIS);
    }
    // cand encoder (single chunk)
    qkv_gemm<<<NCAND * 240, 256, 0, stream>>>(emb, candidates, cand_qkvT, qkv_ws, 0, NCAND);
    attn_pool<<<NCAND * BATCH, 512, 0, stream>>>(qkv_ws, cand_wpT, cand_bp, cand_qv, cand_enc, 0, NCAND);

    encode_user<<<BATCH, 512, 0, stream>>>(news_enc, usr_qkvT, usr_wpT, usr_bp, usr_qv, user_rep);
    score_kernel<<<BATCH, 320, 0, stream>>>(user_rep, cand_enc, out);
}